// Round 17
// baseline (1150.671 us; speedup 1.0000x reference)
//
#include <hip/hip_runtime.h>

typedef unsigned short u16;
typedef unsigned int u32;
typedef u16 u16x8 __attribute__((ext_vector_type(8)));
typedef u16 u16x4 __attribute__((ext_vector_type(4)));
typedef __bf16 bf16x8 __attribute__((ext_vector_type(8)));
typedef float f32x4 __attribute__((ext_vector_type(4)));

#define DEV __device__ __forceinline__

DEV u16 f2bf(float f) {
  u32 u = __builtin_bit_cast(u32, f);
  u32 r = u + 0x7fffu + ((u >> 16) & 1u);
  return (u16)(r >> 16);
}

DEV float bf2f(u16 v) { return __builtin_bit_cast(float, (u32)v << 16); }

DEV int imin(int a, int b) { return a < b ? a : b; }

DEV void gload_lds16(const void* g, void* l) {
  __builtin_amdgcn_global_load_lds(
      (const __attribute__((address_space(1))) void*)g,
      (__attribute__((address_space(3))) void*)l, 16, 0, 0);
}

// ============ BMxBN GEMM template: C = A @ Bt^T + bias ============
// 256 thr = 4 waves (2M x 2N); per-wave (BM/2)x(BN/2): MF=BM/32, NF=BN/32 frags.
// BM64/BN256 PIPE0: 40KB LDS, 4 blk/CU — 32 MFMA : 20 ds_read per K-step
//   (2.1x compute per staged byte; R16 win on FF1, R17 propagated to QKV).
// BM64/BN128 PIPE1: 48KB dbuf (FF2 arm, small grid).
// R11 lesson: never force occupancy via launch_bounds min-waves (VGPR spill).
// LDS XOR-swizzled via pre-swizzled global source. Dead M-tiles exit.
// Epilogue bounces C through LDS -> u16x8 coalesced stores.
// VMODE=1 (QKV): n-tiles with n0>=1536 are V -> TRANSPOSED to vT[b,h,d,s]
// (BN=256: V = exactly the last 3 of 9 n-tiles, split stays tile-aligned).
template <int RELU, int VMODE, int PIPE, int BM, int BN>
__global__ __launch_bounds__(256, (PIPE && BM == 128) ? 2 : 3) void gemm97_kernel(
    const u16* __restrict__ A, const u16* __restrict__ Bt, const float* __restrict__ bias,
    u16* __restrict__ Cb, u16* __restrict__ vT, const int* __restrict__ lens, int M, int N, int K,
    int ldc) {
  constexpr int MF = BM / 32;    // A m-frags per wave
  constexpr int NF = BN / 32;    // B n-frags per wave
  constexpr int ASZ = BM * 64;   // A tile u16 count
  constexpr int BSZ = BN * 64;   // B tile u16 count
  __shared__ __align__(16) u16 SB[PIPE ? 2 * ASZ + 2 * BSZ : ASZ + BSZ];
  const int t = threadIdx.x, wave = t >> 6, lane = t & 63;
  const int fr = lane & 15, fq = lane >> 4;
  const int NT = K >> 6;
  const int nbx = N / BN;

  int bid = blockIdx.x;
  {  // XCD-aware swizzle (all grids here are %8==0)
    const int cpx = (int)gridDim.x >> 3;
    bid = (bid & 7) * cpx + (bid >> 3);
  }
  const int bx = bid % nbx, by = bid / nbx;
  const int m0 = by * BM, n0 = bx * BN;
  if ((m0 & 511) >= lens[m0 >> 9]) return;  // dead M-tile

  const int srow = t >> 3;
  const int c8 = ((t & 7) ^ (srow & 7)) * 8;
  const u16* ag = A + (size_t)(m0 + srow) * K + c8;
  const u16* bg = Bt + (size_t)(n0 + srow) * K + c8;

  auto STAGE = [&](int buf, int kt) {
    char* a = (char*)(SB + (PIPE ? buf * ASZ : 0)) + wave * 1024;
    char* b = (char*)(SB + (PIPE ? 2 * ASZ + buf * BSZ : ASZ)) + wave * 1024;
    const u16* agp = ag + (size_t)kt * 64;
    const u16* bgp = bg + (size_t)kt * 64;
#pragma unroll
    for (int i = 0; i < MF; ++i) gload_lds16(agp + (size_t)i * 32 * K, a + i * 4096);
#pragma unroll
    for (int i = 0; i < NF; ++i) gload_lds16(bgp + (size_t)i * 32 * K, b + i * 4096);
  };

  const int wr = (wave >> 1) * (BM / 2), wc = (wave & 1) * (BN / 2);
  f32x4 acc[MF][NF] = {};

  if (PIPE) {
    STAGE(0, 0);
    asm volatile("s_waitcnt vmcnt(0)" ::: "memory");
    __syncthreads();
  }

  for (int kt = 0; kt < NT; ++kt) {
    const int cur = PIPE ? (kt & 1) : 0;
    if (PIPE) {
      if (kt + 1 < NT) STAGE(cur ^ 1, kt + 1);
    } else {
      STAGE(0, kt);
      asm volatile("s_waitcnt vmcnt(0)" ::: "memory");
      __syncthreads();
    }
    const u16* Ab = SB + (PIPE ? cur * ASZ : 0);
    const u16* Bb = SB + (PIPE ? 2 * ASZ + cur * BSZ : ASZ);
#pragma unroll
    for (int ks = 0; ks < 2; ++ks) {
      bf16x8 af[MF], bv[NF];
#pragma unroll
      for (int m = 0; m < MF; ++m)
        af[m] = *(const bf16x8*)(Ab + (wr + m * 16 + fr) * 64 + (((ks * 4 + fq) ^ (fr & 7)) * 8));
#pragma unroll
      for (int n = 0; n < NF; ++n)
        bv[n] = *(const bf16x8*)(Bb + (wc + n * 16 + fr) * 64 + (((ks * 4 + fq) ^ (fr & 7)) * 8));
#pragma unroll
      for (int m = 0; m < MF; ++m)
#pragma unroll
        for (int n = 0; n < NF; ++n)
          acc[m][n] = __builtin_amdgcn_mfma_f32_16x16x32_bf16(af[m], bv[n], acc[m][n], 0, 0, 0);
    }
    if (PIPE) asm volatile("s_waitcnt vmcnt(0)" ::: "memory");
    __syncthreads();
  }

  if (VMODE && n0 >= 1536) {
    // V block: direct transposed u16x4 stores to vT[b,h,d,s]
#pragma unroll
    for (int n = 0; n < NF; ++n) {
      const int col = n0 + wc + n * 16 + fr;
      const float bvv = bias[col];
      const int dd = col - 1536;
      const int hh = dd >> 6, d6 = dd & 63;
#pragma unroll
      for (int m = 0; m < MF; ++m) {
        const int row0 = m0 + wr + m * 16 + fq * 4;
        const int bb = row0 >> 9, ss = row0 & 511;
        u16x4 pk;
#pragma unroll
        for (int r = 0; r < 4; ++r) pk[r] = f2bf(acc[m][n][r] + bvv);
        *(u16x4*)(vT + ((size_t)(bb * 12 + hh) * 64 + d6) * 512 + ss) = pk;
      }
    }
  } else {
    // LDS-bounce epilogue: swizzled LDS writes, then coalesced u16x8 stores
#pragma unroll
    for (int n = 0; n < NF; ++n) {
      const int col = wc + n * 16 + fr;
      const float bvv = bias[n0 + col];
#pragma unroll
      for (int m = 0; m < MF; ++m) {
#pragma unroll
        for (int r = 0; r < 4; ++r) {
          const int row = wr + m * 16 + fq * 4 + r;
          float v = acc[m][n][r] + bvv;
          if (RELU) v = fmaxf(v, 0.f);
          SB[row * BN + (col ^ ((row & 7) << 4))] = f2bf(v);
        }
      }
    }
    __syncthreads();
    constexpr int TPR = BN / 8;     // threads per output row
    constexpr int RPP = 256 / TPR;  // rows per pass
#pragma unroll
    for (int i = 0; i < BM / RPP; ++i) {
      const int row = (t / TPR) + i * RPP;
      const int col8 = (t % TPR) * 8;
      u16x8 vv = *(const u16x8*)(SB + row * BN + (col8 ^ ((row & 7) << 4)));
      *(u16x8*)(Cb + (size_t)(m0 + row) * ldc + n0 + col8) = vv;
    }
  }
}

// ------ attention: qk [B,S,1536] bf16 + vT [B,H,64,512] bf16 -> o [B,S,768] bf16 ------
// One block per (b, h, q-QUARTER): 4 waves x 32 q-rows (Q in registers, 2 frags).
__global__ __launch_bounds__(256) void attn_kernel(const u16* __restrict__ qk,
                                                   const u16* __restrict__ vT,
                                                   const int* __restrict__ lens,
                                                   u16* __restrict__ o) {
  __shared__ __align__(16) u16 Kl[128 * 64];     // K tile [kv][d], swizzled
  __shared__ __align__(16) u16 Vt[64 * 128];     // V^T tile [d][kv], swizzled
  __shared__ __align__(16) u16 Pl[4][16 * 128];  // per-wave P

  const int bid = blockIdx.x;
  const int qq = bid & 3;
  const int pair = bid >> 2;
  const int h = pair % 12;
  const int b = pair / 12;
  const int len = lens[b];
  if (qq * 128 >= len) return;  // dead q-quarter
  const int t = threadIdx.x, wave = t >> 6, lane = t & 63;
  const int fr = lane & 15, fq = lane >> 4;

  const size_t base = (size_t)b * 512 * 1536;
  const size_t vbase = (size_t)(b * 12 + h) * 64 * 512;
  const int q0w = qq * 128 + wave * 32;

  bf16x8 qf[2][2];
#pragma unroll
  for (int qi = 0; qi < 2; ++qi)
#pragma unroll
    for (int ks = 0; ks < 2; ++ks)
      qf[qi][ks] = *(const bf16x8*)(qk + base + (size_t)(q0w + qi * 16 + fr) * 1536 + h * 64 +
                                    ks * 32 + fq * 8);

  f32x4 oacc[2][4] = {};
  float mrow[2][4], lrow[2][4];
#pragma unroll
  for (int qi = 0; qi < 2; ++qi)
#pragma unroll
    for (int r = 0; r < 4; ++r) {
      mrow[qi][r] = -1e30f;
      lrow[qi][r] = 0.f;
    }

  const int nt = (len + 127) >> 7;  // block-uniform
  for (int kt = 0; kt < nt; ++kt) {
    const int kv0 = kt * 128;
#pragma unroll
    for (int i = 0; i < 4; ++i) {
      const int c = i * 256 + t;
      const int krow = c >> 3, kch = c & 7;
      u16x8 kvl = *(const u16x8*)(qk + base + (size_t)(kv0 + krow) * 1536 + 768 + h * 64 + kch * 8);
      *(u16x8*)(Kl + krow * 64 + ((kch ^ (krow & 7)) * 8)) = kvl;
      const int d = c >> 4, vch = c & 15;
      u16x8 vv = *(const u16x8*)(vT + vbase + (size_t)d * 512 + kv0 + vch * 8);
      *(u16x8*)(Vt + d * 128 + ((vch ^ (d & 7)) * 8)) = vv;
    }
    __syncthreads();

#pragma unroll
    for (int qi = 0; qi < 2; ++qi) {
      if (q0w + qi * 16 >= len) break;  // wave-uniform, no barriers inside
      f32x4 sa[8] = {};
#pragma unroll
      for (int ks = 0; ks < 2; ++ks) {
#pragma unroll
        for (int n = 0; n < 8; ++n) {
          const int colr = n * 16 + fr;
          bf16x8 kf = *(const bf16x8*)(Kl + colr * 64 + (((ks * 4 + fq) ^ (colr & 7)) * 8));
          sa[n] = __builtin_amdgcn_mfma_f32_16x16x32_bf16(qf[qi][ks], kf, sa[n], 0, 0, 0);
        }
      }

      float tm[4] = {-1e30f, -1e30f, -1e30f, -1e30f};
#pragma unroll
      for (int n = 0; n < 8; ++n) {
        const int col = kv0 + n * 16 + fr;
        const bool ok = col < len;
#pragma unroll
        for (int r = 0; r < 4; ++r) {
          const float s = ok ? sa[n][r] * 0.125f : -1e30f;
          sa[n][r] = s;
          tm[r] = fmaxf(tm[r], s);
        }
      }
#pragma unroll
      for (int d = 1; d < 16; d <<= 1)
#pragma unroll
        for (int r = 0; r < 4; ++r) tm[r] = fmaxf(tm[r], __shfl_xor(tm[r], d));

      float al[4], rs[4];
#pragma unroll
      for (int r = 0; r < 4; ++r) {
        const float mn = fmaxf(mrow[qi][r], tm[r]);
        al[r] = __expf(mrow[qi][r] - mn);
        mrow[qi][r] = mn;
        rs[r] = 0.f;
      }
#pragma unroll
      for (int n = 0; n < 8; ++n)
#pragma unroll
        for (int r = 0; r < 4; ++r) {
          const float p = __expf(sa[n][r] - mrow[qi][r]);
          sa[n][r] = p;
          rs[r] += p;
        }
#pragma unroll
      for (int d = 1; d < 16; d <<= 1)
#pragma unroll
        for (int r = 0; r < 4; ++r) rs[r] += __shfl_xor(rs[r], d);
#pragma unroll
      for (int r = 0; r < 4; ++r) lrow[qi][r] = lrow[qi][r] * al[r] + rs[r];
#pragma unroll
      for (int n = 0; n < 4; ++n)
#pragma unroll
        for (int r = 0; r < 4; ++r) oacc[qi][n][r] *= al[r];

      u16* P = &Pl[wave][0];
#pragma unroll
      for (int n = 0; n < 8; ++n) {
        const int col = n * 16 + fr;
#pragma unroll
        for (int r = 0; r < 4; ++r) {
          const int row = fq * 4 + r;
          P[row * 128 + (((col >> 3) ^ (row & 7)) * 8) + (col & 7)] = f2bf(sa[n][r]);
        }
      }
      // PV: wave reads only its own P region; in-wave lgkmcnt ordering suffices
#pragma unroll
      for (int kslot = 0; kslot < 4; ++kslot) {
        const int ch = kslot * 4 + fq;
        bf16x8 pa = *(const bf16x8*)(P + fr * 128 + ((ch ^ (fr & 7)) * 8));
#pragma unroll
        for (int n = 0; n < 4; ++n) {
          const int colv = n * 16 + fr;
          bf16x8 vf = *(const bf16x8*)(Vt + colv * 128 + ((ch ^ (colv & 7)) * 8));
          oacc[qi][n] = __builtin_amdgcn_mfma_f32_16x16x32_bf16(pa, vf, oacc[qi][n], 0, 0, 0);
        }
      }
    }
    __syncthreads();  // all waves done with Kl/Vt before next tile's staging
  }

  const size_t obase = (size_t)b * 512 * 768 + (size_t)q0w * 768 + h * 64;
#pragma unroll
  for (int qi = 0; qi < 2; ++qi) {
    if (q0w + qi * 16 >= len) break;
#pragma unroll
    for (int n = 0; n < 4; ++n)
#pragma unroll
      for (int r = 0; r < 4; ++r)
        o[obase + (size_t)(qi * 16 + fq * 4 + r) * 768 + n * 16 + fr] =
            f2bf(oacc[qi][n][r] / lrow[qi][r]);
  }
}

// -------- ALL weight transposes (6 layers x {q,k,v,w1,w2}) in one dispatch --------
// per 64x64 tile: out[n][k] = f2bf(in[k][n]); ~67us across 3 variants (R4/R5/R7)
// -> HBM-pattern-bound, leave as-is.
__global__ __launch_bounds__(256) void transpose_all_kernel(
    const float* __restrict__ qw, const float* __restrict__ kw, const float* __restrict__ vw,
    const float* __restrict__ w1, const float* __restrict__ w2, u16* __restrict__ qkvt6,
    u16* __restrict__ w1t6, u16* __restrict__ w2t6) {
  __shared__ float tile[64][65];
  const int l = blockIdx.y;
  int x = blockIdx.x;
  const float* in;
  u16* op;
  int K, N, nbx;
  if (x < 432) {
    const int which = x / 144;
    x -= which * 144;
    in = (which == 0 ? qw : which == 1 ? kw : vw) + (size_t)l * 768 * 768;
    op = qkvt6 + (size_t)l * 2304 * 768 + (size_t)which * 768 * 768;
    K = 768;
    N = 768;
    nbx = 12;
  } else if (x < 1008) {
    x -= 432;
    in = w1 + (size_t)l * 768 * 3072;
    op = w1t6 + (size_t)l * 3072 * 768;
    K = 768;
    N = 3072;
    nbx = 48;
  } else {
    x -= 1008;
    in = w2 + (size_t)l * 3072 * 768;
    op = w2t6 + (size_t)l * 768 * 3072;
    K = 3072;
    N = 768;
    nbx = 12;
  }
  const int tx = threadIdx.x & 63, ty = threadIdx.x >> 6;
  const int n0 = (x % nbx) * 64, k0 = (x / nbx) * 64;
#pragma unroll
  for (int i = 0; i < 16; ++i)
    tile[ty + i * 4][tx] = in[(size_t)(k0 + ty + i * 4) * N + n0 + tx];
  __syncthreads();
#pragma unroll
  for (int i = 0; i < 16; ++i)
    op[(size_t)(n0 + ty + i * 4) * K + k0 + tx] = f2bf(tile[tx][ty + i * 4]);
}

// ---------------- input projection: bf16-only residual stream ----------------
__global__ __launch_bounds__(256) void inproj_kernel(const float* __restrict__ x,
                                                     const float* __restrict__ in_w,
                                                     const float* __restrict__ in_b,
                                                     const float* __restrict__ pos,
                                                     u16* __restrict__ hbf) {
  __shared__ float xs[8][32];
  const int t = threadIdx.x;
  const int row0 = blockIdx.x * 8;
  xs[t >> 5][t & 31] = x[(size_t)row0 * 32 + t];
  __syncthreads();
#pragma unroll
  for (int j = 0; j < 3; ++j) {
    const int d = t + j * 256;
    float acc[8] = {};
#pragma unroll
    for (int i = 0; i < 32; ++i) {
      const float wv = in_w[i * 768 + d];
#pragma unroll
      for (int r = 0; r < 8; ++r) acc[r] += xs[r][i] * wv;
    }
    const float bb = in_b[d];
#pragma unroll
    for (int r = 0; r < 8; ++r) {
      const int row = row0 + r;
      const int s = row & 511;
      hbf[(size_t)row * 768 + d] = f2bf(acc[r] + bb + pos[(size_t)s * 768 + d]);
    }
  }
}

// -------- LayerNorm(h_bf16 + delta_bf16) -> h_bf16: wave-per-row; dead rows skip --------
__global__ __launch_bounds__(256) void ln_kernel(u16* __restrict__ hbf,
                                                 const u16* __restrict__ delta,
                                                 const int* __restrict__ lens,
                                                 const float* __restrict__ g,
                                                 const float* __restrict__ bb) {
  const int row = blockIdx.x * 4 + (threadIdx.x >> 6);
  if ((row & 511) >= lens[row >> 9]) return;  // dead row (no barriers below)
  const int lane = threadIdx.x & 63;
  const size_t rb = (size_t)row * 768 + lane * 4;
  f32x4 xv[3];
  float s = 0.f, s2 = 0.f;
#pragma unroll
  for (int j = 0; j < 3; ++j) {
    u16x4 a = *(const u16x4*)(hbf + rb + j * 256);
    u16x4 dv = *(const u16x4*)(delta + rb + j * 256);
    f32x4 v;
#pragma unroll
    for (int c = 0; c < 4; ++c) v[c] = bf2f(a[c]) + bf2f(dv[c]);
    xv[j] = v;
    s += v[0] + v[1] + v[2] + v[3];
    s2 += v[0] * v[0] + v[1] * v[1] + v[2] * v[2] + v[3] * v[3];
  }
#pragma unroll
  for (int d = 1; d < 64; d <<= 1) {
    s += __shfl_xor(s, d);
    s2 += __shfl_xor(s2, d);
  }
  const float mean = s * (1.f / 768.f);
  const float var = fmaxf(s2 * (1.f / 768.f) - mean * mean, 0.f);
  const float rstd = rsqrtf(var + 1e-5f);
#pragma unroll
  for (int j = 0; j < 3; ++j) {
    f32x4 gv = *(const f32x4*)(g + lane * 4 + j * 256);
    f32x4 bv = *(const f32x4*)(bb + lane * 4 + j * 256);
    u16x4 yb;
#pragma unroll
    for (int c = 0; c < 4; ++c) yb[c] = f2bf((xv[j][c] - mean) * rstd * gv[c] + bv[c]);
    *(u16x4*)(hbf + rb + j * 256) = yb;
  }
}

// ---------------- masked mean pool + out projection (2-stage, bf16 h) ----------------
__global__ __launch_bounds__(256) void pool1_kernel(const u16* __restrict__ h,
                                                    const int* __restrict__ lens,
                                                    const float* __restrict__ ow,
                                                    float* __restrict__ wsp) {
  const int b = blockIdx.x >> 3, chunk = blockIdx.x & 7;
  const int len = lens[b];
  const int t = threadIdx.x;
  const int s0 = chunk * 64;
  const int s1 = imin(s0 + 64, len);
  float acc0 = 0.f, acc1 = 0.f, acc2 = 0.f;
  const u16* hp = h + (size_t)b * 512 * 768;
  for (int s = s0; s < s1; ++s) {
    const size_t rb = (size_t)s * 768;
    acc0 += bf2f(hp[rb + t]);
    acc1 += bf2f(hp[rb + t + 256]);
    acc2 += bf2f(hp[rb + t + 512]);
  }
  float part = acc0 * ow[t] + acc1 * ow[t + 256] + acc2 * ow[t + 512];
#pragma unroll
  for (int d = 1; d < 64; d <<= 1) part += __shfl_xor(part, d);
  __shared__ float ps[4];
  if ((t & 63) == 0) ps[t >> 6] = part;
  __syncthreads();
  if (t == 0) wsp[blockIdx.x] = ps[0] + ps[1] + ps[2] + ps[3];
}

__global__ void pool2_kernel(const float* __restrict__ wsp, const int* __restrict__ lens,
                             const float* __restrict__ ob, float* __restrict__ out) {
  const int b = threadIdx.x;
  if (b < 16) {
    float s = 0.f;
#pragma unroll
    for (int c = 0; c < 8; ++c) s += wsp[b * 8 + c];
    out[b] = s / (float)lens[b] + ob[0];
  }
}

__global__ void biaspack_kernel(const float* __restrict__ qb, const float* __restrict__ kb,
                                const float* __restrict__ vb, float* __restrict__ qkvb) {
  const int i = blockIdx.x * 256 + threadIdx.x;
  if (i >= 6 * 2304) return;
  const int l = i / 2304, j = i % 2304;
  float v;
  if (j < 768)
    v = qb[l * 768 + j];
  else if (j < 1536)
    v = kb[l * 768 + j - 768];
  else
    v = vb[l * 768 + j - 1536];
  qkvb[i] = v;
}

extern "C" void kernel_launch(void* const* d_in, const int* in_sizes, int n_in, void* d_out,
                              int out_size, void* d_ws, size_t ws_size, hipStream_t stream) {
  const float* x = (const float*)d_in[0];
  const int* lens = (const int*)d_in[1];
  const float* in_w = (const float*)d_in[2];
  const float* in_b = (const float*)d_in[3];
  const float* pos = (const float*)d_in[4];
  const float* qw = (const float*)d_in[5];
  const float* qb = (const float*)d_in[6];
  const float* kw = (const float*)d_in[7];
  const float* kb = (const float*)d_in[8];
  const float* vw = (const float*)d_in[9];
  const float* vb = (const float*)d_in[10];
  const float* w1 = (const float*)d_in[11];
  const float* b1 = (const float*)d_in[12];
  const float* w2 = (const float*)d_in[13];
  const float* b2 = (const float*)d_in[14];
  const float* ln1g = (const float*)d_in[15];
  const float* ln1b = (const float*)d_in[16];
  const float* ln2g = (const float*)d_in[17];
  const float* ln2b = (const float*)d_in[18];
  const float* ow = (const float*)d_in[19];
  const float* ob = (const float*)d_in[20];
  float* out = (float*)d_out;

  char* w = (char*)d_ws;
  size_t off = 0;
  auto alloc = [&](size_t bytes) -> void* {
    void* p = w + off;
    off += (bytes + 255) & ~(size_t)255;
    return p;
  };
  u16* qkvt6 = (u16*)alloc((size_t)6 * 2304 * 768 * 2);
  u16* w1t6 = (u16*)alloc((size_t)6 * 3072 * 768 * 2);
  u16* w2t6 = (u16*)alloc((size_t)6 * 768 * 3072 * 2);
  float* qkvb = (float*)alloc((size_t)6 * 2304 * 4);
  u16* hbf = (u16*)alloc((size_t)8192 * 768 * 2);    // bf16-only residual stream
  u16* obuf = (u16*)alloc((size_t)8192 * 768 * 2);   // attn-out / FF2-out (bf16)
  u16* ubuf = (u16*)alloc((size_t)8192 * 3072 * 2);  // union: {qk + vT} / ff
  float* wsp = (float*)alloc((size_t)128 * 4);
  u16* qkbuf = ubuf;                     // [8192][1536]
  u16* vT = ubuf + (size_t)8192 * 1536;  // [192][64][512]
  u16* ffbuf = ubuf;                     // [8192][3072] (after attn done)

  biaspack_kernel<<<(6 * 2304 + 255) / 256, 256, 0, stream>>>(qb, kb, vb, qkvb);
  transpose_all_kernel<<<dim3(1584, 6), 256, 0, stream>>>(qw, kw, vw, w1, w2, qkvt6, w1t6, w2t6);
  inproj_kernel<<<1024, 256, 0, stream>>>(x, in_w, in_b, pos, hbf);

  for (int l = 0; l < 6; ++l) {
    // QKV: BM=64/BN=256, PIPE=0 (R17 treatment; V region = last 3 n-tiles)
    gemm97_kernel<0, 1, 0, 64, 256><<<1152, 256, 0, stream>>>(
        hbf, qkvt6 + (size_t)l * 2304 * 768, qkvb + l * 2304, qkbuf, vT, lens, 8192, 2304, 768,
        1536);
    attn_kernel<<<768, 256, 0, stream>>>(qkbuf, vT, lens, obuf);
    ln_kernel<<<2048, 256, 0, stream>>>(hbf, obuf, lens, ln1g + l * 768, ln1b + l * 768);
    // FF1: BM=64/BN=256, PIPE=0 (R16 winner)
    gemm97_kernel<1, 0, 0, 64, 256><<<1536, 256, 0, stream>>>(
        hbf, w1t6 + (size_t)l * 3072 * 768, b1 + l * 3072, ffbuf, nullptr, lens, 8192, 3072, 768,
        3072);
    // FF2: BM=64/BN=128, PIPE=1 (control; N=768 too small for BN=256 grid)
    gemm97_kernel<0, 0, 1, 64, 128><<<768, 256, 0, stream>>>(
        ffbuf, w2t6 + (size_t)l * 768 * 3072, b2 + l * 768, obuf, nullptr, lens, 8192, 768, 3072,
        768);
    ln_kernel<<<2048, 256, 0, stream>>>(hbf, obuf, lens, ln2g + l * 768, ln2b + l * 768);
  }
  pool1_kernel<<<128, 256, 0, stream>>>(hbf, lens, ow, wsp);
  pool2_kernel<<<1, 64, 0, stream>>>(wsp, lens, ob, out);
  (void)in_sizes;
  (void)n_in;
  (void)out_size;
  (void)ws_size;
}

// Round 18
// 1142.238 us; speedup vs baseline: 1.0074x; 1.0074x over previous
//
#include <hip/hip_runtime.h>

typedef unsigned short u16;
typedef unsigned int u32;
typedef u16 u16x8 __attribute__((ext_vector_type(8)));
typedef u16 u16x4 __attribute__((ext_vector_type(4)));
typedef __bf16 bf16x8 __attribute__((ext_vector_type(8)));
typedef float f32x4 __attribute__((ext_vector_type(4)));

#define DEV __device__ __forceinline__

DEV u16 f2bf(float f) {
  u32 u = __builtin_bit_cast(u32, f);
  u32 r = u + 0x7fffu + ((u >> 16) & 1u);
  return (u16)(r >> 16);
}

DEV float bf2f(u16 v) { return __builtin_bit_cast(float, (u32)v << 16); }

DEV int imin(int a, int b) { return a < b ? a : b; }

DEV void gload_lds16(const void* g, void* l) {
  __builtin_amdgcn_global_load_lds(
      (const __attribute__((address_space(1))) void*)g,
      (__attribute__((address_space(3))) void*)l, 16, 0, 0);
}

// ============ BMxBN GEMM template: C = A @ Bt^T + bias ============
// 256 thr = 4 waves (2M x 2N); per-wave (BM/2)x(BN/2): MF=BM/32, NF=BN/32 frags.
// Measured tile-space (R12-R17): QKV best = BM64/BN128/PIPE0 (TLP-bound, grid
// 2304); FF1 best = BM64/BN256/PIPE0 (reuse wins, grid stays 1536); FF2 best =
// BM64/BN128/PIPE1 (small grid -> in-block latency hiding). BN256 on QKV was a
// wash (R17): reuse gain offset by halved grid. BM128 lost to BM64 (R13).
// R11 lesson: never force occupancy via launch_bounds min-waves (VGPR spill).
// LDS XOR-swizzled via pre-swizzled global source. Dead M-tiles exit.
// Epilogue bounces C through LDS -> u16x8 coalesced stores.
// VMODE=1 (QKV): n-tiles with n0>=1536 are V -> TRANSPOSED to vT[b,h,d,s].
template <int RELU, int VMODE, int PIPE, int BM, int BN>
__global__ __launch_bounds__(256, (PIPE && BM == 128) ? 2 : 3) void gemm97_kernel(
    const u16* __restrict__ A, const u16* __restrict__ Bt, const float* __restrict__ bias,
    u16* __restrict__ Cb, u16* __restrict__ vT, const int* __restrict__ lens, int M, int N, int K,
    int ldc) {
  constexpr int MF = BM / 32;    // A m-frags per wave
  constexpr int NF = BN / 32;    // B n-frags per wave
  constexpr int ASZ = BM * 64;   // A tile u16 count
  constexpr int BSZ = BN * 64;   // B tile u16 count
  __shared__ __align__(16) u16 SB[PIPE ? 2 * ASZ + 2 * BSZ : ASZ + BSZ];
  const int t = threadIdx.x, wave = t >> 6, lane = t & 63;
  const int fr = lane & 15, fq = lane >> 4;
  const int NT = K >> 6;
  const int nbx = N / BN;

  int bid = blockIdx.x;
  {  // XCD-aware swizzle (all grids here are %8==0)
    const int cpx = (int)gridDim.x >> 3;
    bid = (bid & 7) * cpx + (bid >> 3);
  }
  const int bx = bid % nbx, by = bid / nbx;
  const int m0 = by * BM, n0 = bx * BN;
  if ((m0 & 511) >= lens[m0 >> 9]) return;  // dead M-tile

  const int srow = t >> 3;
  const int c8 = ((t & 7) ^ (srow & 7)) * 8;
  const u16* ag = A + (size_t)(m0 + srow) * K + c8;
  const u16* bg = Bt + (size_t)(n0 + srow) * K + c8;

  auto STAGE = [&](int buf, int kt) {
    char* a = (char*)(SB + (PIPE ? buf * ASZ : 0)) + wave * 1024;
    char* b = (char*)(SB + (PIPE ? 2 * ASZ + buf * BSZ : ASZ)) + wave * 1024;
    const u16* agp = ag + (size_t)kt * 64;
    const u16* bgp = bg + (size_t)kt * 64;
#pragma unroll
    for (int i = 0; i < MF; ++i) gload_lds16(agp + (size_t)i * 32 * K, a + i * 4096);
#pragma unroll
    for (int i = 0; i < NF; ++i) gload_lds16(bgp + (size_t)i * 32 * K, b + i * 4096);
  };

  const int wr = (wave >> 1) * (BM / 2), wc = (wave & 1) * (BN / 2);
  f32x4 acc[MF][NF] = {};

  if (PIPE) {
    STAGE(0, 0);
    asm volatile("s_waitcnt vmcnt(0)" ::: "memory");
    __syncthreads();
  }

  for (int kt = 0; kt < NT; ++kt) {
    const int cur = PIPE ? (kt & 1) : 0;
    if (PIPE) {
      if (kt + 1 < NT) STAGE(cur ^ 1, kt + 1);
    } else {
      STAGE(0, kt);
      asm volatile("s_waitcnt vmcnt(0)" ::: "memory");
      __syncthreads();
    }
    const u16* Ab = SB + (PIPE ? cur * ASZ : 0);
    const u16* Bb = SB + (PIPE ? 2 * ASZ + cur * BSZ : ASZ);
#pragma unroll
    for (int ks = 0; ks < 2; ++ks) {
      bf16x8 af[MF], bv[NF];
#pragma unroll
      for (int m = 0; m < MF; ++m)
        af[m] = *(const bf16x8*)(Ab + (wr + m * 16 + fr) * 64 + (((ks * 4 + fq) ^ (fr & 7)) * 8));
#pragma unroll
      for (int n = 0; n < NF; ++n)
        bv[n] = *(const bf16x8*)(Bb + (wc + n * 16 + fr) * 64 + (((ks * 4 + fq) ^ (fr & 7)) * 8));
#pragma unroll
      for (int m = 0; m < MF; ++m)
#pragma unroll
        for (int n = 0; n < NF; ++n)
          acc[m][n] = __builtin_amdgcn_mfma_f32_16x16x32_bf16(af[m], bv[n], acc[m][n], 0, 0, 0);
    }
    if (PIPE) asm volatile("s_waitcnt vmcnt(0)" ::: "memory");
    __syncthreads();
  }

  if (VMODE && n0 >= 1536) {
    // V block: direct transposed u16x4 stores to vT[b,h,d,s]
#pragma unroll
    for (int n = 0; n < NF; ++n) {
      const int col = n0 + wc + n * 16 + fr;
      const float bvv = bias[col];
      const int dd = col - 1536;
      const int hh = dd >> 6, d6 = dd & 63;
#pragma unroll
      for (int m = 0; m < MF; ++m) {
        const int row0 = m0 + wr + m * 16 + fq * 4;
        const int bb = row0 >> 9, ss = row0 & 511;
        u16x4 pk;
#pragma unroll
        for (int r = 0; r < 4; ++r) pk[r] = f2bf(acc[m][n][r] + bvv);
        *(u16x4*)(vT + ((size_t)(bb * 12 + hh) * 64 + d6) * 512 + ss) = pk;
      }
    }
  } else {
    // LDS-bounce epilogue: swizzled LDS writes, then coalesced u16x8 stores
#pragma unroll
    for (int n = 0; n < NF; ++n) {
      const int col = wc + n * 16 + fr;
      const float bvv = bias[n0 + col];
#pragma unroll
      for (int m = 0; m < MF; ++m) {
#pragma unroll
        for (int r = 0; r < 4; ++r) {
          const int row = wr + m * 16 + fq * 4 + r;
          float v = acc[m][n][r] + bvv;
          if (RELU) v = fmaxf(v, 0.f);
          SB[row * BN + (col ^ ((row & 7) << 4))] = f2bf(v);
        }
      }
    }
    __syncthreads();
    constexpr int TPR = BN / 8;     // threads per output row
    constexpr int RPP = 256 / TPR;  // rows per pass
#pragma unroll
    for (int i = 0; i < BM / RPP; ++i) {
      const int row = (t / TPR) + i * RPP;
      const int col8 = (t % TPR) * 8;
      u16x8 vv = *(const u16x8*)(SB + row * BN + (col8 ^ ((row & 7) << 4)));
      *(u16x8*)(Cb + (size_t)(m0 + row) * ldc + n0 + col8) = vv;
    }
  }
}

// ------ attention: qk [B,S,1536] bf16 + vT [B,H,64,512] bf16 -> o [B,S,768] bf16 ------
// One block per (b, h, q-QUARTER): 4 waves x 32 q-rows (Q in registers, 2 frags).
__global__ __launch_bounds__(256) void attn_kernel(const u16* __restrict__ qk,
                                                   const u16* __restrict__ vT,
                                                   const int* __restrict__ lens,
                                                   u16* __restrict__ o) {
  __shared__ __align__(16) u16 Kl[128 * 64];     // K tile [kv][d], swizzled
  __shared__ __align__(16) u16 Vt[64 * 128];     // V^T tile [d][kv], swizzled
  __shared__ __align__(16) u16 Pl[4][16 * 128];  // per-wave P

  const int bid = blockIdx.x;
  const int qq = bid & 3;
  const int pair = bid >> 2;
  const int h = pair % 12;
  const int b = pair / 12;
  const int len = lens[b];
  if (qq * 128 >= len) return;  // dead q-quarter
  const int t = threadIdx.x, wave = t >> 6, lane = t & 63;
  const int fr = lane & 15, fq = lane >> 4;

  const size_t base = (size_t)b * 512 * 1536;
  const size_t vbase = (size_t)(b * 12 + h) * 64 * 512;
  const int q0w = qq * 128 + wave * 32;

  bf16x8 qf[2][2];
#pragma unroll
  for (int qi = 0; qi < 2; ++qi)
#pragma unroll
    for (int ks = 0; ks < 2; ++ks)
      qf[qi][ks] = *(const bf16x8*)(qk + base + (size_t)(q0w + qi * 16 + fr) * 1536 + h * 64 +
                                    ks * 32 + fq * 8);

  f32x4 oacc[2][4] = {};
  float mrow[2][4], lrow[2][4];
#pragma unroll
  for (int qi = 0; qi < 2; ++qi)
#pragma unroll
    for (int r = 0; r < 4; ++r) {
      mrow[qi][r] = -1e30f;
      lrow[qi][r] = 0.f;
    }

  const int nt = (len + 127) >> 7;  // block-uniform
  for (int kt = 0; kt < nt; ++kt) {
    const int kv0 = kt * 128;
#pragma unroll
    for (int i = 0; i < 4; ++i) {
      const int c = i * 256 + t;
      const int krow = c >> 3, kch = c & 7;
      u16x8 kvl = *(const u16x8*)(qk + base + (size_t)(kv0 + krow) * 1536 + 768 + h * 64 + kch * 8);
      *(u16x8*)(Kl + krow * 64 + ((kch ^ (krow & 7)) * 8)) = kvl;
      const int d = c >> 4, vch = c & 15;
      u16x8 vv = *(const u16x8*)(vT + vbase + (size_t)d * 512 + kv0 + vch * 8);
      *(u16x8*)(Vt + d * 128 + ((vch ^ (d & 7)) * 8)) = vv;
    }
    __syncthreads();

#pragma unroll
    for (int qi = 0; qi < 2; ++qi) {
      if (q0w + qi * 16 >= len) break;  // wave-uniform, no barriers inside
      f32x4 sa[8] = {};
#pragma unroll
      for (int ks = 0; ks < 2; ++ks) {
#pragma unroll
        for (int n = 0; n < 8; ++n) {
          const int colr = n * 16 + fr;
          bf16x8 kf = *(const bf16x8*)(Kl + colr * 64 + (((ks * 4 + fq) ^ (colr & 7)) * 8));
          sa[n] = __builtin_amdgcn_mfma_f32_16x16x32_bf16(qf[qi][ks], kf, sa[n], 0, 0, 0);
        }
      }

      float tm[4] = {-1e30f, -1e30f, -1e30f, -1e30f};
#pragma unroll
      for (int n = 0; n < 8; ++n) {
        const int col = kv0 + n * 16 + fr;
        const bool ok = col < len;
#pragma unroll
        for (int r = 0; r < 4; ++r) {
          const float s = ok ? sa[n][r] * 0.125f : -1e30f;
          sa[n][r] = s;
          tm[r] = fmaxf(tm[r], s);
        }
      }
#pragma unroll
      for (int d = 1; d < 16; d <<= 1)
#pragma unroll
        for (int r = 0; r < 4; ++r) tm[r] = fmaxf(tm[r], __shfl_xor(tm[r], d));

      float al[4], rs[4];
#pragma unroll
      for (int r = 0; r < 4; ++r) {
        const float mn = fmaxf(mrow[qi][r], tm[r]);
        al[r] = __expf(mrow[qi][r] - mn);
        mrow[qi][r] = mn;
        rs[r] = 0.f;
      }
#pragma unroll
      for (int n = 0; n < 8; ++n)
#pragma unroll
        for (int r = 0; r < 4; ++r) {
          const float p = __expf(sa[n][r] - mrow[qi][r]);
          sa[n][r] = p;
          rs[r] += p;
        }
#pragma unroll
      for (int d = 1; d < 16; d <<= 1)
#pragma unroll
        for (int r = 0; r < 4; ++r) rs[r] += __shfl_xor(rs[r], d);
#pragma unroll
      for (int r = 0; r < 4; ++r) lrow[qi][r] = lrow[qi][r] * al[r] + rs[r];
#pragma unroll
      for (int n = 0; n < 4; ++n)
#pragma unroll
        for (int r = 0; r < 4; ++r) oacc[qi][n][r] *= al[r];

      u16* P = &Pl[wave][0];
#pragma unroll
      for (int n = 0; n < 8; ++n) {
        const int col = n * 16 + fr;
#pragma unroll
        for (int r = 0; r < 4; ++r) {
          const int row = fq * 4 + r;
          P[row * 128 + (((col >> 3) ^ (row & 7)) * 8) + (col & 7)] = f2bf(sa[n][r]);
        }
      }
      // PV: wave reads only its own P region; in-wave lgkmcnt ordering suffices
#pragma unroll
      for (int kslot = 0; kslot < 4; ++kslot) {
        const int ch = kslot * 4 + fq;
        bf16x8 pa = *(const bf16x8*)(P + fr * 128 + ((ch ^ (fr & 7)) * 8));
#pragma unroll
        for (int n = 0; n < 4; ++n) {
          const int colv = n * 16 + fr;
          bf16x8 vf = *(const bf16x8*)(Vt + colv * 128 + ((ch ^ (colv & 7)) * 8));
          oacc[qi][n] = __builtin_amdgcn_mfma_f32_16x16x32_bf16(pa, vf, oacc[qi][n], 0, 0, 0);
        }
      }
    }
    __syncthreads();  // all waves done with Kl/Vt before next tile's staging
  }

  const size_t obase = (size_t)b * 512 * 768 + (size_t)q0w * 768 + h * 64;
#pragma unroll
  for (int qi = 0; qi < 2; ++qi) {
    if (q0w + qi * 16 >= len) break;
#pragma unroll
    for (int n = 0; n < 4; ++n)
#pragma unroll
      for (int r = 0; r < 4; ++r)
        o[obase + (size_t)(qi * 16 + fq * 4 + r) * 768 + n * 16 + fr] =
            f2bf(oacc[qi][n][r] / lrow[qi][r]);
  }
}

// -------- ALL weight transposes (6 layers x {q,k,v,w1,w2}) in one dispatch --------
// per 64x64 tile: out[n][k] = f2bf(in[k][n]); ~67us across 3 variants (R4/R5/R7)
// -> HBM-pattern-bound, leave as-is.
__global__ __launch_bounds__(256) void transpose_all_kernel(
    const float* __restrict__ qw, const float* __restrict__ kw, const float* __restrict__ vw,
    const float* __restrict__ w1, const float* __restrict__ w2, u16* __restrict__ qkvt6,
    u16* __restrict__ w1t6, u16* __restrict__ w2t6) {
  __shared__ float tile[64][65];
  const int l = blockIdx.y;
  int x = blockIdx.x;
  const float* in;
  u16* op;
  int K, N, nbx;
  if (x < 432) {
    const int which = x / 144;
    x -= which * 144;
    in = (which == 0 ? qw : which == 1 ? kw : vw) + (size_t)l * 768 * 768;
    op = qkvt6 + (size_t)l * 2304 * 768 + (size_t)which * 768 * 768;
    K = 768;
    N = 768;
    nbx = 12;
  } else if (x < 1008) {
    x -= 432;
    in = w1 + (size_t)l * 768 * 3072;
    op = w1t6 + (size_t)l * 3072 * 768;
    K = 768;
    N = 3072;
    nbx = 48;
  } else {
    x -= 1008;
    in = w2 + (size_t)l * 3072 * 768;
    op = w2t6 + (size_t)l * 768 * 3072;
    K = 3072;
    N = 768;
    nbx = 12;
  }
  const int tx = threadIdx.x & 63, ty = threadIdx.x >> 6;
  const int n0 = (x % nbx) * 64, k0 = (x / nbx) * 64;
#pragma unroll
  for (int i = 0; i < 16; ++i)
    tile[ty + i * 4][tx] = in[(size_t)(k0 + ty + i * 4) * N + n0 + tx];
  __syncthreads();
#pragma unroll
  for (int i = 0; i < 16; ++i)
    op[(size_t)(n0 + ty + i * 4) * K + k0 + tx] = f2bf(tile[tx][ty + i * 4]);
}

// ---------------- input projection: bf16-only residual stream ----------------
__global__ __launch_bounds__(256) void inproj_kernel(const float* __restrict__ x,
                                                     const float* __restrict__ in_w,
                                                     const float* __restrict__ in_b,
                                                     const float* __restrict__ pos,
                                                     u16* __restrict__ hbf) {
  __shared__ float xs[8][32];
  const int t = threadIdx.x;
  const int row0 = blockIdx.x * 8;
  xs[t >> 5][t & 31] = x[(size_t)row0 * 32 + t];
  __syncthreads();
#pragma unroll
  for (int j = 0; j < 3; ++j) {
    const int d = t + j * 256;
    float acc[8] = {};
#pragma unroll
    for (int i = 0; i < 32; ++i) {
      const float wv = in_w[i * 768 + d];
#pragma unroll
      for (int r = 0; r < 8; ++r) acc[r] += xs[r][i] * wv;
    }
    const float bb = in_b[d];
#pragma unroll
    for (int r = 0; r < 8; ++r) {
      const int row = row0 + r;
      const int s = row & 511;
      hbf[(size_t)row * 768 + d] = f2bf(acc[r] + bb + pos[(size_t)s * 768 + d]);
    }
  }
}

// -------- LayerNorm(h_bf16 + delta_bf16) -> h_bf16: wave-per-row; dead rows skip --------
__global__ __launch_bounds__(256) void ln_kernel(u16* __restrict__ hbf,
                                                 const u16* __restrict__ delta,
                                                 const int* __restrict__ lens,
                                                 const float* __restrict__ g,
                                                 const float* __restrict__ bb) {
  const int row = blockIdx.x * 4 + (threadIdx.x >> 6);
  if ((row & 511) >= lens[row >> 9]) return;  // dead row (no barriers below)
  const int lane = threadIdx.x & 63;
  const size_t rb = (size_t)row * 768 + lane * 4;
  f32x4 xv[3];
  float s = 0.f, s2 = 0.f;
#pragma unroll
  for (int j = 0; j < 3; ++j) {
    u16x4 a = *(const u16x4*)(hbf + rb + j * 256);
    u16x4 dv = *(const u16x4*)(delta + rb + j * 256);
    f32x4 v;
#pragma unroll
    for (int c = 0; c < 4; ++c) v[c] = bf2f(a[c]) + bf2f(dv[c]);
    xv[j] = v;
    s += v[0] + v[1] + v[2] + v[3];
    s2 += v[0] * v[0] + v[1] * v[1] + v[2] * v[2] + v[3] * v[3];
  }
#pragma unroll
  for (int d = 1; d < 64; d <<= 1) {
    s += __shfl_xor(s, d);
    s2 += __shfl_xor(s2, d);
  }
  const float mean = s * (1.f / 768.f);
  const float var = fmaxf(s2 * (1.f / 768.f) - mean * mean, 0.f);
  const float rstd = rsqrtf(var + 1e-5f);
#pragma unroll
  for (int j = 0; j < 3; ++j) {
    f32x4 gv = *(const f32x4*)(g + lane * 4 + j * 256);
    f32x4 bv = *(const f32x4*)(bb + lane * 4 + j * 256);
    u16x4 yb;
#pragma unroll
    for (int c = 0; c < 4; ++c) yb[c] = f2bf((xv[j][c] - mean) * rstd * gv[c] + bv[c]);
    *(u16x4*)(hbf + rb + j * 256) = yb;
  }
}

// ---------------- masked mean pool + out projection (2-stage, bf16 h) ----------------
__global__ __launch_bounds__(256) void pool1_kernel(const u16* __restrict__ h,
                                                    const int* __restrict__ lens,
                                                    const float* __restrict__ ow,
                                                    float* __restrict__ wsp) {
  const int b = blockIdx.x >> 3, chunk = blockIdx.x & 7;
  const int len = lens[b];
  const int t = threadIdx.x;
  const int s0 = chunk * 64;
  const int s1 = imin(s0 + 64, len);
  float acc0 = 0.f, acc1 = 0.f, acc2 = 0.f;
  const u16* hp = h + (size_t)b * 512 * 768;
  for (int s = s0; s < s1; ++s) {
    const size_t rb = (size_t)s * 768;
    acc0 += bf2f(hp[rb + t]);
    acc1 += bf2f(hp[rb + t + 256]);
    acc2 += bf2f(hp[rb + t + 512]);
  }
  float part = acc0 * ow[t] + acc1 * ow[t + 256] + acc2 * ow[t + 512];
#pragma unroll
  for (int d = 1; d < 64; d <<= 1) part += __shfl_xor(part, d);
  __shared__ float ps[4];
  if ((t & 63) == 0) ps[t >> 6] = part;
  __syncthreads();
  if (t == 0) wsp[blockIdx.x] = ps[0] + ps[1] + ps[2] + ps[3];
}

__global__ void pool2_kernel(const float* __restrict__ wsp, const int* __restrict__ lens,
                             const float* __restrict__ ob, float* __restrict__ out) {
  const int b = threadIdx.x;
  if (b < 16) {
    float s = 0.f;
#pragma unroll
    for (int c = 0; c < 8; ++c) s += wsp[b * 8 + c];
    out[b] = s / (float)lens[b] + ob[0];
  }
}

__global__ void biaspack_kernel(const float* __restrict__ qb, const float* __restrict__ kb,
                                const float* __restrict__ vb, float* __restrict__ qkvb) {
  const int i = blockIdx.x * 256 + threadIdx.x;
  if (i >= 6 * 2304) return;
  const int l = i / 2304, j = i % 2304;
  float v;
  if (j < 768)
    v = qb[l * 768 + j];
  else if (j < 1536)
    v = kb[l * 768 + j - 768];
  else
    v = vb[l * 768 + j - 1536];
  qkvb[i] = v;
}

extern "C" void kernel_launch(void* const* d_in, const int* in_sizes, int n_in, void* d_out,
                              int out_size, void* d_ws, size_t ws_size, hipStream_t stream) {
  const float* x = (const float*)d_in[0];
  const int* lens = (const int*)d_in[1];
  const float* in_w = (const float*)d_in[2];
  const float* in_b = (const float*)d_in[3];
  const float* pos = (const float*)d_in[4];
  const float* qw = (const float*)d_in[5];
  const float* qb = (const float*)d_in[6];
  const float* kw = (const float*)d_in[7];
  const float* kb = (const float*)d_in[8];
  const float* vw = (const float*)d_in[9];
  const float* vb = (const float*)d_in[10];
  const float* w1 = (const float*)d_in[11];
  const float* b1 = (const float*)d_in[12];
  const float* w2 = (const float*)d_in[13];
  const float* b2 = (const float*)d_in[14];
  const float* ln1g = (const float*)d_in[15];
  const float* ln1b = (const float*)d_in[16];
  const float* ln2g = (const float*)d_in[17];
  const float* ln2b = (const float*)d_in[18];
  const float* ow = (const float*)d_in[19];
  const float* ob = (const float*)d_in[20];
  float* out = (float*)d_out;

  char* w = (char*)d_ws;
  size_t off = 0;
  auto alloc = [&](size_t bytes) -> void* {
    void* p = w + off;
    off += (bytes + 255) & ~(size_t)255;
    return p;
  };
  u16* qkvt6 = (u16*)alloc((size_t)6 * 2304 * 768 * 2);
  u16* w1t6 = (u16*)alloc((size_t)6 * 3072 * 768 * 2);
  u16* w2t6 = (u16*)alloc((size_t)6 * 768 * 3072 * 2);
  float* qkvb = (float*)alloc((size_t)6 * 2304 * 4);
  u16* hbf = (u16*)alloc((size_t)8192 * 768 * 2);    // bf16-only residual stream
  u16* obuf = (u16*)alloc((size_t)8192 * 768 * 2);   // attn-out / FF2-out (bf16)
  u16* ubuf = (u16*)alloc((size_t)8192 * 3072 * 2);  // union: {qk + vT} / ff
  float* wsp = (float*)alloc((size_t)128 * 4);
  u16* qkbuf = ubuf;                     // [8192][1536]
  u16* vT = ubuf + (size_t)8192 * 1536;  // [192][64][512]
  u16* ffbuf = ubuf;                     // [8192][3072] (after attn done)

  biaspack_kernel<<<(6 * 2304 + 255) / 256, 256, 0, stream>>>(qb, kb, vb, qkvb);
  transpose_all_kernel<<<dim3(1584, 6), 256, 0, stream>>>(qw, kw, vw, w1, w2, qkvt6, w1t6, w2t6);
  inproj_kernel<<<1024, 256, 0, stream>>>(x, in_w, in_b, pos, hbf);

  for (int l = 0; l < 6; ++l) {
    // QKV: BM=64/BN=128, PIPE=0 (measured winner; BN256 was a wash - R17)
    gemm97_kernel<0, 1, 0, 64, 128><<<2304, 256, 0, stream>>>(
        hbf, qkvt6 + (size_t)l * 2304 * 768, qkvb + l * 2304, qkbuf, vT, lens, 8192, 2304, 768,
        1536);
    attn_kernel<<<768, 256, 0, stream>>>(qkbuf, vT, lens, obuf);
    ln_kernel<<<2048, 256, 0, stream>>>(hbf, obuf, lens, ln1g + l * 768, ln1b + l * 768);
    // FF1: BM=64/BN=256, PIPE=0 (R16 winner)
    gemm97_kernel<1, 0, 0, 64, 256><<<1536, 256, 0, stream>>>(
        hbf, w1t6 + (size_t)l * 3072 * 768, b1 + l * 3072, ffbuf, nullptr, lens, 8192, 3072, 768,
        3072);
    // FF2: BM=64/BN=128, PIPE=1 (small grid, K=3072)
    gemm97_kernel<0, 0, 1, 64, 128><<<768, 256, 0, stream>>>(
        ffbuf, w2t6 + (size_t)l * 768 * 3072, b2 + l * 768, obuf, nullptr, lens, 8192, 768, 3072,
        768);
    ln_kernel<<<2048, 256, 0, stream>>>(hbf, obuf, lens, ln2g + l * 768, ln2b + l * 768);
  }
  pool1_kernel<<<128, 256, 0, stream>>>(hbf, lens, ow, wsp);
  pool2_kernel<<<1, 64, 0, stream>>>(wsp, lens, ob, out);
  (void)in_sizes;
  (void)n_in;
  (void)out_size;
  (void)ws_size;
}

// Round 19
// 1140.396 us; speedup vs baseline: 1.0090x; 1.0016x over previous
//
#include <hip/hip_runtime.h>

typedef unsigned short u16;
typedef unsigned int u32;
typedef u16 u16x8 __attribute__((ext_vector_type(8)));
typedef u16 u16x4 __attribute__((ext_vector_type(4)));
typedef __bf16 bf16x8 __attribute__((ext_vector_type(8)));
typedef float f32x4 __attribute__((ext_vector_type(4)));

#define DEV __device__ __forceinline__

DEV u16 f2bf(float f) {
  u32 u = __builtin_bit_cast(u32, f);
  u32 r = u + 0x7fffu + ((u >> 16) & 1u);
  return (u16)(r >> 16);
}

DEV float bf2f(u16 v) { return __builtin_bit_cast(float, (u32)v << 16); }

DEV int imin(int a, int b) { return a < b ? a : b; }

DEV void gload_lds16(const void* g, void* l) {
  __builtin_amdgcn_global_load_lds(
      (const __attribute__((address_space(1))) void*)g,
      (__attribute__((address_space(3))) void*)l, 16, 0, 0);
}

// ============ BMxBN GEMM template: C = A @ Bt^T + bias ============
// 256 thr = 4 waves (2M x 2N); per-wave (BM/2)x(BN/2): MF=BM/32, NF=BN/32 frags.
// Measured tile-space (R12-R17): QKV best = BM64/BN128/PIPE0 (TLP-bound, grid
// 2304); FF1 best = BM64/BN256/PIPE0 (reuse wins, grid stays 1536); FF2 best =
// BM64/BN128/PIPE1 (small grid -> in-block latency hiding). BN256 on QKV was a
// wash (R17): reuse gain offset by halved grid. BM128 lost to BM64 (R13).
// R11 lesson: never force occupancy via launch_bounds min-waves (VGPR spill).
// LDS XOR-swizzled via pre-swizzled global source. Dead M-tiles exit.
// Epilogue bounces C through LDS -> u16x8 coalesced stores.
// VMODE=1 (QKV): n-tiles with n0>=1536 are V -> TRANSPOSED to vT[b,h,d,s].
template <int RELU, int VMODE, int PIPE, int BM, int BN>
__global__ __launch_bounds__(256, (PIPE && BM == 128) ? 2 : 3) void gemm97_kernel(
    const u16* __restrict__ A, const u16* __restrict__ Bt, const float* __restrict__ bias,
    u16* __restrict__ Cb, u16* __restrict__ vT, const int* __restrict__ lens, int M, int N, int K,
    int ldc) {
  constexpr int MF = BM / 32;    // A m-frags per wave
  constexpr int NF = BN / 32;    // B n-frags per wave
  constexpr int ASZ = BM * 64;   // A tile u16 count
  constexpr int BSZ = BN * 64;   // B tile u16 count
  __shared__ __align__(16) u16 SB[PIPE ? 2 * ASZ + 2 * BSZ : ASZ + BSZ];
  const int t = threadIdx.x, wave = t >> 6, lane = t & 63;
  const int fr = lane & 15, fq = lane >> 4;
  const int NT = K >> 6;
  const int nbx = N / BN;

  int bid = blockIdx.x;
  {  // XCD-aware swizzle (all grids here are %8==0)
    const int cpx = (int)gridDim.x >> 3;
    bid = (bid & 7) * cpx + (bid >> 3);
  }
  const int bx = bid % nbx, by = bid / nbx;
  const int m0 = by * BM, n0 = bx * BN;
  if ((m0 & 511) >= lens[m0 >> 9]) return;  // dead M-tile

  const int srow = t >> 3;
  const int c8 = ((t & 7) ^ (srow & 7)) * 8;
  const u16* ag = A + (size_t)(m0 + srow) * K + c8;
  const u16* bg = Bt + (size_t)(n0 + srow) * K + c8;

  auto STAGE = [&](int buf, int kt) {
    char* a = (char*)(SB + (PIPE ? buf * ASZ : 0)) + wave * 1024;
    char* b = (char*)(SB + (PIPE ? 2 * ASZ + buf * BSZ : ASZ)) + wave * 1024;
    const u16* agp = ag + (size_t)kt * 64;
    const u16* bgp = bg + (size_t)kt * 64;
#pragma unroll
    for (int i = 0; i < MF; ++i) gload_lds16(agp + (size_t)i * 32 * K, a + i * 4096);
#pragma unroll
    for (int i = 0; i < NF; ++i) gload_lds16(bgp + (size_t)i * 32 * K, b + i * 4096);
  };

  const int wr = (wave >> 1) * (BM / 2), wc = (wave & 1) * (BN / 2);
  f32x4 acc[MF][NF] = {};

  if (PIPE) {
    STAGE(0, 0);
    asm volatile("s_waitcnt vmcnt(0)" ::: "memory");
    __syncthreads();
  }

  for (int kt = 0; kt < NT; ++kt) {
    const int cur = PIPE ? (kt & 1) : 0;
    if (PIPE) {
      if (kt + 1 < NT) STAGE(cur ^ 1, kt + 1);
    } else {
      STAGE(0, kt);
      asm volatile("s_waitcnt vmcnt(0)" ::: "memory");
      __syncthreads();
    }
    const u16* Ab = SB + (PIPE ? cur * ASZ : 0);
    const u16* Bb = SB + (PIPE ? 2 * ASZ + cur * BSZ : ASZ);
#pragma unroll
    for (int ks = 0; ks < 2; ++ks) {
      bf16x8 af[MF], bv[NF];
#pragma unroll
      for (int m = 0; m < MF; ++m)
        af[m] = *(const bf16x8*)(Ab + (wr + m * 16 + fr) * 64 + (((ks * 4 + fq) ^ (fr & 7)) * 8));
#pragma unroll
      for (int n = 0; n < NF; ++n)
        bv[n] = *(const bf16x8*)(Bb + (wc + n * 16 + fr) * 64 + (((ks * 4 + fq) ^ (fr & 7)) * 8));
#pragma unroll
      for (int m = 0; m < MF; ++m)
#pragma unroll
        for (int n = 0; n < NF; ++n)
          acc[m][n] = __builtin_amdgcn_mfma_f32_16x16x32_bf16(af[m], bv[n], acc[m][n], 0, 0, 0);
    }
    if (PIPE) asm volatile("s_waitcnt vmcnt(0)" ::: "memory");
    __syncthreads();
  }

  if (VMODE && n0 >= 1536) {
    // V block: direct transposed u16x4 stores to vT[b,h,d,s]
#pragma unroll
    for (int n = 0; n < NF; ++n) {
      const int col = n0 + wc + n * 16 + fr;
      const float bvv = bias[col];
      const int dd = col - 1536;
      const int hh = dd >> 6, d6 = dd & 63;
#pragma unroll
      for (int m = 0; m < MF; ++m) {
        const int row0 = m0 + wr + m * 16 + fq * 4;
        const int bb = row0 >> 9, ss = row0 & 511;
        u16x4 pk;
#pragma unroll
        for (int r = 0; r < 4; ++r) pk[r] = f2bf(acc[m][n][r] + bvv);
        *(u16x4*)(vT + ((size_t)(bb * 12 + hh) * 64 + d6) * 512 + ss) = pk;
      }
    }
  } else {
    // LDS-bounce epilogue: swizzled LDS writes, then coalesced u16x8 stores
#pragma unroll
    for (int n = 0; n < NF; ++n) {
      const int col = wc + n * 16 + fr;
      const float bvv = bias[n0 + col];
#pragma unroll
      for (int m = 0; m < MF; ++m) {
#pragma unroll
        for (int r = 0; r < 4; ++r) {
          const int row = wr + m * 16 + fq * 4 + r;
          float v = acc[m][n][r] + bvv;
          if (RELU) v = fmaxf(v, 0.f);
          SB[row * BN + (col ^ ((row & 7) << 4))] = f2bf(v);
        }
      }
    }
    __syncthreads();
    constexpr int TPR = BN / 8;     // threads per output row
    constexpr int RPP = 256 / TPR;  // rows per pass
#pragma unroll
    for (int i = 0; i < BM / RPP; ++i) {
      const int row = (t / TPR) + i * RPP;
      const int col8 = (t % TPR) * 8;
      u16x8 vv = *(const u16x8*)(SB + row * BN + (col8 ^ ((row & 7) << 4)));
      *(u16x8*)(Cb + (size_t)(m0 + row) * ldc + n0 + col8) = vv;
    }
  }
}

// ------ attention: qk [B,S,1536] bf16 + vT [B,H,64,512] bf16 -> o [B,S,768] bf16 ------
// One block per (b, h, q-QUARTER): 4 waves x 32 q-rows (Q in registers, 2 frags).
__global__ __launch_bounds__(256) void attn_kernel(const u16* __restrict__ qk,
                                                   const u16* __restrict__ vT,
                                                   const int* __restrict__ lens,
                                                   u16* __restrict__ o) {
  __shared__ __align__(16) u16 Kl[128 * 64];     // K tile [kv][d], swizzled
  __shared__ __align__(16) u16 Vt[64 * 128];     // V^T tile [d][kv], swizzled
  __shared__ __align__(16) u16 Pl[4][16 * 128];  // per-wave P

  const int bid = blockIdx.x;
  const int qq = bid & 3;
  const int pair = bid >> 2;
  const int h = pair % 12;
  const int b = pair / 12;
  const int len = lens[b];
  if (qq * 128 >= len) return;  // dead q-quarter
  const int t = threadIdx.x, wave = t >> 6, lane = t & 63;
  const int fr = lane & 15, fq = lane >> 4;

  const size_t base = (size_t)b * 512 * 1536;
  const size_t vbase = (size_t)(b * 12 + h) * 64 * 512;
  const int q0w = qq * 128 + wave * 32;

  bf16x8 qf[2][2];
#pragma unroll
  for (int qi = 0; qi < 2; ++qi)
#pragma unroll
    for (int ks = 0; ks < 2; ++ks)
      qf[qi][ks] = *(const bf16x8*)(qk + base + (size_t)(q0w + qi * 16 + fr) * 1536 + h * 64 +
                                    ks * 32 + fq * 8);

  f32x4 oacc[2][4] = {};
  float mrow[2][4], lrow[2][4];
#pragma unroll
  for (int qi = 0; qi < 2; ++qi)
#pragma unroll
    for (int r = 0; r < 4; ++r) {
      mrow[qi][r] = -1e30f;
      lrow[qi][r] = 0.f;
    }

  const int nt = (len + 127) >> 7;  // block-uniform
  for (int kt = 0; kt < nt; ++kt) {
    const int kv0 = kt * 128;
#pragma unroll
    for (int i = 0; i < 4; ++i) {
      const int c = i * 256 + t;
      const int krow = c >> 3, kch = c & 7;
      u16x8 kvl = *(const u16x8*)(qk + base + (size_t)(kv0 + krow) * 1536 + 768 + h * 64 + kch * 8);
      *(u16x8*)(Kl + krow * 64 + ((kch ^ (krow & 7)) * 8)) = kvl;
      const int d = c >> 4, vch = c & 15;
      u16x8 vv = *(const u16x8*)(vT + vbase + (size_t)d * 512 + kv0 + vch * 8);
      *(u16x8*)(Vt + d * 128 + ((vch ^ (d & 7)) * 8)) = vv;
    }
    __syncthreads();

#pragma unroll
    for (int qi = 0; qi < 2; ++qi) {
      if (q0w + qi * 16 >= len) break;  // wave-uniform, no barriers inside
      f32x4 sa[8] = {};
#pragma unroll
      for (int ks = 0; ks < 2; ++ks) {
#pragma unroll
        for (int n = 0; n < 8; ++n) {
          const int colr = n * 16 + fr;
          bf16x8 kf = *(const bf16x8*)(Kl + colr * 64 + (((ks * 4 + fq) ^ (colr & 7)) * 8));
          sa[n] = __builtin_amdgcn_mfma_f32_16x16x32_bf16(qf[qi][ks], kf, sa[n], 0, 0, 0);
        }
      }

      float tm[4] = {-1e30f, -1e30f, -1e30f, -1e30f};
#pragma unroll
      for (int n = 0; n < 8; ++n) {
        const int col = kv0 + n * 16 + fr;
        const bool ok = col < len;
#pragma unroll
        for (int r = 0; r < 4; ++r) {
          const float s = ok ? sa[n][r] * 0.125f : -1e30f;
          sa[n][r] = s;
          tm[r] = fmaxf(tm[r], s);
        }
      }
#pragma unroll
      for (int d = 1; d < 16; d <<= 1)
#pragma unroll
        for (int r = 0; r < 4; ++r) tm[r] = fmaxf(tm[r], __shfl_xor(tm[r], d));

      float al[4], rs[4];
#pragma unroll
      for (int r = 0; r < 4; ++r) {
        const float mn = fmaxf(mrow[qi][r], tm[r]);
        al[r] = __expf(mrow[qi][r] - mn);
        mrow[qi][r] = mn;
        rs[r] = 0.f;
      }
#pragma unroll
      for (int n = 0; n < 8; ++n)
#pragma unroll
        for (int r = 0; r < 4; ++r) {
          const float p = __expf(sa[n][r] - mrow[qi][r]);
          sa[n][r] = p;
          rs[r] += p;
        }
#pragma unroll
      for (int d = 1; d < 16; d <<= 1)
#pragma unroll
        for (int r = 0; r < 4; ++r) rs[r] += __shfl_xor(rs[r], d);
#pragma unroll
      for (int r = 0; r < 4; ++r) lrow[qi][r] = lrow[qi][r] * al[r] + rs[r];
#pragma unroll
      for (int n = 0; n < 4; ++n)
#pragma unroll
        for (int r = 0; r < 4; ++r) oacc[qi][n][r] *= al[r];

      u16* P = &Pl[wave][0];
#pragma unroll
      for (int n = 0; n < 8; ++n) {
        const int col = n * 16 + fr;
#pragma unroll
        for (int r = 0; r < 4; ++r) {
          const int row = fq * 4 + r;
          P[row * 128 + (((col >> 3) ^ (row & 7)) * 8) + (col & 7)] = f2bf(sa[n][r]);
        }
      }
      // PV: wave reads only its own P region; in-wave lgkmcnt ordering suffices
#pragma unroll
      for (int kslot = 0; kslot < 4; ++kslot) {
        const int ch = kslot * 4 + fq;
        bf16x8 pa = *(const bf16x8*)(P + fr * 128 + ((ch ^ (fr & 7)) * 8));
#pragma unroll
        for (int n = 0; n < 4; ++n) {
          const int colv = n * 16 + fr;
          bf16x8 vf = *(const bf16x8*)(Vt + colv * 128 + ((ch ^ (colv & 7)) * 8));
          oacc[qi][n] = __builtin_amdgcn_mfma_f32_16x16x32_bf16(pa, vf, oacc[qi][n], 0, 0, 0);
        }
      }
    }
    __syncthreads();  // all waves done with Kl/Vt before next tile's staging
  }

  const size_t obase = (size_t)b * 512 * 768 + (size_t)q0w * 768 + h * 64;
#pragma unroll
  for (int qi = 0; qi < 2; ++qi) {
    if (q0w + qi * 16 >= len) break;
#pragma unroll
    for (int n = 0; n < 4; ++n)
#pragma unroll
      for (int r = 0; r < 4; ++r)
        o[obase + (size_t)(qi * 16 + fq * 4 + r) * 768 + n * 16 + fr] =
            f2bf(oacc[qi][n][r] / lrow[qi][r]);
  }
}

// -------- ALL weight transposes (6 layers x {q,k,v,w1,w2}) in one dispatch --------
// per 64x64 tile: out[n][k] = f2bf(in[k][n]); ~67us across 3 variants (R4/R5/R7)
// -> HBM-pattern-bound, leave as-is.
__global__ __launch_bounds__(256) void transpose_all_kernel(
    const float* __restrict__ qw, const float* __restrict__ kw, const float* __restrict__ vw,
    const float* __restrict__ w1, const float* __restrict__ w2, u16* __restrict__ qkvt6,
    u16* __restrict__ w1t6, u16* __restrict__ w2t6) {
  __shared__ float tile[64][65];
  const int l = blockIdx.y;
  int x = blockIdx.x;
  const float* in;
  u16* op;
  int K, N, nbx;
  if (x < 432) {
    const int which = x / 144;
    x -= which * 144;
    in = (which == 0 ? qw : which == 1 ? kw : vw) + (size_t)l * 768 * 768;
    op = qkvt6 + (size_t)l * 2304 * 768 + (size_t)which * 768 * 768;
    K = 768;
    N = 768;
    nbx = 12;
  } else if (x < 1008) {
    x -= 432;
    in = w1 + (size_t)l * 768 * 3072;
    op = w1t6 + (size_t)l * 3072 * 768;
    K = 768;
    N = 3072;
    nbx = 48;
  } else {
    x -= 1008;
    in = w2 + (size_t)l * 3072 * 768;
    op = w2t6 + (size_t)l * 768 * 3072;
    K = 3072;
    N = 768;
    nbx = 12;
  }
  const int tx = threadIdx.x & 63, ty = threadIdx.x >> 6;
  const int n0 = (x % nbx) * 64, k0 = (x / nbx) * 64;
#pragma unroll
  for (int i = 0; i < 16; ++i)
    tile[ty + i * 4][tx] = in[(size_t)(k0 + ty + i * 4) * N + n0 + tx];
  __syncthreads();
#pragma unroll
  for (int i = 0; i < 16; ++i)
    op[(size_t)(n0 + ty + i * 4) * K + k0 + tx] = f2bf(tile[tx][ty + i * 4]);
}

// ---------------- input projection: bf16-only residual stream ----------------
__global__ __launch_bounds__(256) void inproj_kernel(const float* __restrict__ x,
                                                     const float* __restrict__ in_w,
                                                     const float* __restrict__ in_b,
                                                     const float* __restrict__ pos,
                                                     u16* __restrict__ hbf) {
  __shared__ float xs[8][32];
  const int t = threadIdx.x;
  const int row0 = blockIdx.x * 8;
  xs[t >> 5][t & 31] = x[(size_t)row0 * 32 + t];
  __syncthreads();
#pragma unroll
  for (int j = 0; j < 3; ++j) {
    const int d = t + j * 256;
    float acc[8] = {};
#pragma unroll
    for (int i = 0; i < 32; ++i) {
      const float wv = in_w[i * 768 + d];
#pragma unroll
      for (int r = 0; r < 8; ++r) acc[r] += xs[r][i] * wv;
    }
    const float bb = in_b[d];
#pragma unroll
    for (int r = 0; r < 8; ++r) {
      const int row = row0 + r;
      const int s = row & 511;
      hbf[(size_t)row * 768 + d] = f2bf(acc[r] + bb + pos[(size_t)s * 768 + d]);
    }
  }
}

// -------- LayerNorm(h_bf16 + delta_bf16) -> h_bf16: wave-per-row; dead rows skip --------
__global__ __launch_bounds__(256) void ln_kernel(u16* __restrict__ hbf,
                                                 const u16* __restrict__ delta,
                                                 const int* __restrict__ lens,
                                                 const float* __restrict__ g,
                                                 const float* __restrict__ bb) {
  const int row = blockIdx.x * 4 + (threadIdx.x >> 6);
  if ((row & 511) >= lens[row >> 9]) return;  // dead row (no barriers below)
  const int lane = threadIdx.x & 63;
  const size_t rb = (size_t)row * 768 + lane * 4;
  f32x4 xv[3];
  float s = 0.f, s2 = 0.f;
#pragma unroll
  for (int j = 0; j < 3; ++j) {
    u16x4 a = *(const u16x4*)(hbf + rb + j * 256);
    u16x4 dv = *(const u16x4*)(delta + rb + j * 256);
    f32x4 v;
#pragma unroll
    for (int c = 0; c < 4; ++c) v[c] = bf2f(a[c]) + bf2f(dv[c]);
    xv[j] = v;
    s += v[0] + v[1] + v[2] + v[3];
    s2 += v[0] * v[0] + v[1] * v[1] + v[2] * v[2] + v[3] * v[3];
  }
#pragma unroll
  for (int d = 1; d < 64; d <<= 1) {
    s += __shfl_xor(s, d);
    s2 += __shfl_xor(s2, d);
  }
  const float mean = s * (1.f / 768.f);
  const float var = fmaxf(s2 * (1.f / 768.f) - mean * mean, 0.f);
  const float rstd = rsqrtf(var + 1e-5f);
#pragma unroll
  for (int j = 0; j < 3; ++j) {
    f32x4 gv = *(const f32x4*)(g + lane * 4 + j * 256);
    f32x4 bv = *(const f32x4*)(bb + lane * 4 + j * 256);
    u16x4 yb;
#pragma unroll
    for (int c = 0; c < 4; ++c) yb[c] = f2bf((xv[j][c] - mean) * rstd * gv[c] + bv[c]);
    *(u16x4*)(hbf + rb + j * 256) = yb;
  }
}

// ---------------- masked mean pool + out projection (2-stage, bf16 h) ----------------
__global__ __launch_bounds__(256) void pool1_kernel(const u16* __restrict__ h,
                                                    const int* __restrict__ lens,
                                                    const float* __restrict__ ow,
                                                    float* __restrict__ wsp) {
  const int b = blockIdx.x >> 3, chunk = blockIdx.x & 7;
  const int len = lens[b];
  const int t = threadIdx.x;
  const int s0 = chunk * 64;
  const int s1 = imin(s0 + 64, len);
  float acc0 = 0.f, acc1 = 0.f, acc2 = 0.f;
  const u16* hp = h + (size_t)b * 512 * 768;
  for (int s = s0; s < s1; ++s) {
    const size_t rb = (size_t)s * 768;
    acc0 += bf2f(hp[rb + t]);
    acc1 += bf2f(hp[rb + t + 256]);
    acc2 += bf2f(hp[rb + t + 512]);
  }
  float part = acc0 * ow[t] + acc1 * ow[t + 256] + acc2 * ow[t + 512];
#pragma unroll
  for (int d = 1; d < 64; d <<= 1) part += __shfl_xor(part, d);
  __shared__ float ps[4];
  if ((t & 63) == 0) ps[t >> 6] = part;
  __syncthreads();
  if (t == 0) wsp[blockIdx.x] = ps[0] + ps[1] + ps[2] + ps[3];
}

__global__ void pool2_kernel(const float* __restrict__ wsp, const int* __restrict__ lens,
                             const float* __restrict__ ob, float* __restrict__ out) {
  const int b = threadIdx.x;
  if (b < 16) {
    float s = 0.f;
#pragma unroll
    for (int c = 0; c < 8; ++c) s += wsp[b * 8 + c];
    out[b] = s / (float)lens[b] + ob[0];
  }
}

__global__ void biaspack_kernel(const float* __restrict__ qb, const float* __restrict__ kb,
                                const float* __restrict__ vb, float* __restrict__ qkvb) {
  const int i = blockIdx.x * 256 + threadIdx.x;
  if (i >= 6 * 2304) return;
  const int l = i / 2304, j = i % 2304;
  float v;
  if (j < 768)
    v = qb[l * 768 + j];
  else if (j < 1536)
    v = kb[l * 768 + j - 768];
  else
    v = vb[l * 768 + j - 1536];
  qkvb[i] = v;
}

extern "C" void kernel_launch(void* const* d_in, const int* in_sizes, int n_in, void* d_out,
                              int out_size, void* d_ws, size_t ws_size, hipStream_t stream) {
  const float* x = (const float*)d_in[0];
  const int* lens = (const int*)d_in[1];
  const float* in_w = (const float*)d_in[2];
  const float* in_b = (const float*)d_in[3];
  const float* pos = (const float*)d_in[4];
  const float* qw = (const float*)d_in[5];
  const float* qb = (const float*)d_in[6];
  const float* kw = (const float*)d_in[7];
  const float* kb = (const float*)d_in[8];
  const float* vw = (const float*)d_in[9];
  const float* vb = (const float*)d_in[10];
  const float* w1 = (const float*)d_in[11];
  const float* b1 = (const float*)d_in[12];
  const float* w2 = (const float*)d_in[13];
  const float* b2 = (const float*)d_in[14];
  const float* ln1g = (const float*)d_in[15];
  const float* ln1b = (const float*)d_in[16];
  const float* ln2g = (const float*)d_in[17];
  const float* ln2b = (const float*)d_in[18];
  const float* ow = (const float*)d_in[19];
  const float* ob = (const float*)d_in[20];
  float* out = (float*)d_out;

  char* w = (char*)d_ws;
  size_t off = 0;
  auto alloc = [&](size_t bytes) -> void* {
    void* p = w + off;
    off += (bytes + 255) & ~(size_t)255;
    return p;
  };
  u16* qkvt6 = (u16*)alloc((size_t)6 * 2304 * 768 * 2);
  u16* w1t6 = (u16*)alloc((size_t)6 * 3072 * 768 * 2);
  u16* w2t6 = (u16*)alloc((size_t)6 * 768 * 3072 * 2);
  float* qkvb = (float*)alloc((size_t)6 * 2304 * 4);
  u16* hbf = (u16*)alloc((size_t)8192 * 768 * 2);    // bf16-only residual stream
  u16* obuf = (u16*)alloc((size_t)8192 * 768 * 2);   // attn-out / FF2-out (bf16)
  u16* ubuf = (u16*)alloc((size_t)8192 * 3072 * 2);  // union: {qk + vT} / ff
  float* wsp = (float*)alloc((size_t)128 * 4);
  u16* qkbuf = ubuf;                     // [8192][1536]
  u16* vT = ubuf + (size_t)8192 * 1536;  // [192][64][512]
  u16* ffbuf = ubuf;                     // [8192][3072] (after attn done)

  biaspack_kernel<<<(6 * 2304 + 255) / 256, 256, 0, stream>>>(qb, kb, vb, qkvb);
  transpose_all_kernel<<<dim3(1584, 6), 256, 0, stream>>>(qw, kw, vw, w1, w2, qkvt6, w1t6, w2t6);
  inproj_kernel<<<1024, 256, 0, stream>>>(x, in_w, in_b, pos, hbf);

  for (int l = 0; l < 6; ++l) {
    // QKV: BM=64/BN=128, PIPE=0 (measured winner; BN256 was a wash - R17)
    gemm97_kernel<0, 1, 0, 64, 128><<<2304, 256, 0, stream>>>(
        hbf, qkvt6 + (size_t)l * 2304 * 768, qkvb + l * 2304, qkbuf, vT, lens, 8192, 2304, 768,
        1536);
    attn_kernel<<<768, 256, 0, stream>>>(qkbuf, vT, lens, obuf);
    ln_kernel<<<2048, 256, 0, stream>>>(hbf, obuf, lens, ln1g + l * 768, ln1b + l * 768);
    // FF1: BM=64/BN=256, PIPE=0 (R16 winner)
    gemm97_kernel<1, 0, 0, 64, 256><<<1536, 256, 0, stream>>>(
        hbf, w1t6 + (size_t)l * 3072 * 768, b1 + l * 3072, ffbuf, nullptr, lens, 8192, 3072, 768,
        3072);
    // FF2: BM=64/BN=128, PIPE=1 (small grid, K=3072)
    gemm97_kernel<0, 0, 1, 64, 128><<<768, 256, 0, stream>>>(
        ffbuf, w2t6 + (size_t)l * 768 * 3072, b2 + l * 768, obuf, nullptr, lens, 8192, 768, 3072,
        768);
    ln_kernel<<<2048, 256, 0, stream>>>(hbf, obuf, lens, ln2g + l * 768, ln2b + l * 768);
  }
  pool1_kernel<<<128, 256, 0, stream>>>(hbf, lens, ow, wsp);
  pool2_kernel<<<1, 64, 0, stream>>>(wsp, lens, ob, out);
  (void)in_sizes;
  (void)n_in;
  (void)out_size;
  (void)ws_size;
}